// Round 5
// baseline (209.473 us; speedup 1.0000x reference)
//
#include <hip/hip_runtime.h>

using u16 = unsigned short;
using u32 = unsigned int;

typedef __bf16 bf16x8 __attribute__((ext_vector_type(8)));
typedef float f32x4 __attribute__((ext_vector_type(4)));

#define T_SEQ 2048
#define NC 1024
#define HDIM 64
#define WINSZ 256
#define QSTEP (2.0f / 255.0f)

__device__ __forceinline__ float b2f(u16 u) {
  u32 v = ((u32)u) << 16;
  return __builtin_bit_cast(float, v);
}
__device__ __forceinline__ u16 f2b(float f) {
  u32 x = __builtin_bit_cast(u32, f);
  u32 r = (x + 0x7fffu + ((x >> 16) & 1u)) >> 16;  // RNE
  return (u16)r;
}
__device__ __forceinline__ float quantize(float v) {
  v = fminf(fmaxf(v, -1.0f), 1.0f);
  return QSTEP * rintf(v / QSTEP);
}

// ---- prep: z=0 transpose w_attn, z=1 transpose w_proj, z=2 convert x (all fp32 -> bf16) ----
__global__ __launch_bounds__(256) void k1_prep(const float* __restrict__ x, u16* __restrict__ xb,
                                               const float* __restrict__ wa, u16* __restrict__ wTa,
                                               const float* __restrict__ wp, u16* __restrict__ wTp) {
  if (blockIdx.z == 2) {  // x convert, vectorized x4, grid-stride
    const int nb = gridDim.x * gridDim.y;
    const int bid = blockIdx.y * gridDim.x + blockIdx.x;
    const int n4 = T_SEQ * NC / 4;
    for (int i = bid * 256 + threadIdx.x; i < n4; i += nb * 256) {
      const float4 v = ((const float4*)x)[i];
      ushort4 o;
      o.x = f2b(v.x); o.y = f2b(v.y); o.z = f2b(v.z); o.w = f2b(v.w);
      ((ushort4*)xb)[i] = o;
    }
    return;
  }
  const int iswp = (blockIdx.z == 1);
  if (iswp && blockIdx.x >= 16) return;
  const float* in = iswp ? wp : wa;
  u16* out = iswp ? wTp : wTa;
  const int Cc = iswp ? 1024 : 3072;
  __shared__ u16 tile[64][65];
  const int tc = blockIdx.x * 64, tr = blockIdx.y * 64;
  const int lx = threadIdx.x & 63, ly = threadIdx.x >> 6;
#pragma unroll
  for (int r = ly; r < 64; r += 4)
    tile[r][lx] = f2b(in[(long)(tr + r) * Cc + tc + lx]);
  __syncthreads();
#pragma unroll
  for (int r = ly; r < 64; r += 4) out[(tc + r) * 1024 + tr + lx] = tile[lx][r];
}

// ---- qkv GEMM: 64x128 tile, BK=64, 2-phase dbuf, COALESCED REG-STAGING ----
// Coalesced chunk map row=id>>3,sl=id&7: wave reads 8 rows x 128B contiguous = 16 full cache
// lines per global_load_dwordx4 (old map: row=lane -> 64 lines/instr at 2KB stride; txn-path
// bound ~48us, insensitive to pipelining/occupancy per R1/R2 nulls).
// Staging is global->reg->LDS (ds_write_b128); XOR bank-swizzle applied at the per-lane
// ds_write (slot^row&7), matching read slot = kc^(ln15&7). No global_load_lds used.
__global__ __launch_bounds__(256, 3) void k2_qkv(const u16* __restrict__ A,
                                                 const u16* __restrict__ BT,
                                                 u16* __restrict__ o0, u16* __restrict__ o1,
                                                 u16* __restrict__ o2) {
  __shared__ __align__(16) u16 As[2][4096];  // [buf][row:64][slot:8][8]   8KB each
  __shared__ __align__(16) u16 Bs[2][8192];  // [buf][row:128][slot:8][8] 16KB each
  const int tid = threadIdx.x;
  const int lane = tid & 63;
  const int wave = tid >> 6;
  const int wr = wave >> 1, wc = wave & 1;  // wave: rows wr*32+[0,32), cols wc*64+[0,64)
  const int ln15 = lane & 15, lq = lane >> 4;
  const int l7 = ln15 & 7;

  // XCD-locality swizzle: 768 blocks, 8 XCDs, 96 contiguous tiles/XCD (bijective: 768%8==0)
  const int wg = blockIdx.y * 24 + blockIdx.x;
  const int lin = (wg & 7) * 96 + (wg >> 3);
  const int by = lin / 24;  // [0,32) M-tile
  const int bx = lin % 24;  // [0,24) N-tile
  const int m0 = by * 64, n0 = bx * 128;

  // staging: A 512 chunks, B 1024 chunks of 16B; 2+4 per thread
  const u16* ag[2];
  const u16* bg[4];
  int awofs[2], bwofs[4];
#pragma unroll
  for (int i = 0; i < 2; i++) {
    const int id = tid + i * 256;          // [0,512)
    const int row = id >> 3, sl = id & 7;  // A: [row:64][slot:8]
    ag[i] = A + (m0 + row) * NC + sl * 8;  // plain coalesced source
    awofs[i] = (row * 8 + (sl ^ (row & 7))) * 8;  // XOR swizzle at LDS write
  }
#pragma unroll
  for (int i = 0; i < 4; i++) {
    const int id = tid + i * 256;          // [0,1024)
    const int row = id >> 3, sl = id & 7;  // B: [row:128][slot:8]
    bg[i] = BT + (n0 + row) * NC + sl * 8;
    bwofs[i] = (row * 8 + (sl ^ (row & 7))) * 8;
  }

  uint4 ra[2], rb[4];
  f32x4 acc[2][4] = {};

  auto load_regs = [&](int ktv) {
#pragma unroll
    for (int i = 0; i < 2; i++) ra[i] = *(const uint4*)(ag[i] + ktv);
#pragma unroll
    for (int i = 0; i < 4; i++) rb[i] = *(const uint4*)(bg[i] + ktv);
  };
  auto write_lds = [&](u16* LA, u16* LB) {
#pragma unroll
    for (int i = 0; i < 2; i++) *(uint4*)&LA[awofs[i]] = ra[i];
#pragma unroll
    for (int i = 0; i < 4; i++) *(uint4*)&LB[bwofs[i]] = rb[i];
  };
  auto compute = [&](const u16* LA, const u16* LB) {
#pragma unroll
    for (int s = 0; s < 2; s++) {
      const int kc = s * 4 + lq;
      const int sw = kc ^ l7;  // swizzled slot (row&7 == l7 for all fragment rows)
      bf16x8 af[2], bfr[4];
#pragma unroll
      for (int r = 0; r < 2; r++) {
        const int ar = wr * 32 + r * 16 + ln15;
        af[r] = *(const bf16x8*)&LA[(ar * 8 + sw) * 8];
      }
#pragma unroll
      for (int c = 0; c < 4; c++) {
        const int br = wc * 64 + c * 16 + ln15;
        bfr[c] = *(const bf16x8*)&LB[(br * 8 + sw) * 8];
      }
#pragma unroll
      for (int r = 0; r < 2; r++)
#pragma unroll
        for (int c = 0; c < 4; c++)
          acc[r][c] = __builtin_amdgcn_mfma_f32_16x16x32_bf16(af[r], bfr[c], acc[r][c], 0, 0, 0);
    }
  };

  // prologue: tile 0 -> regs -> buf0
  load_regs(0);
  write_lds(As[0], Bs[0]);

  // 2-phase: top barrier publishes buf writes; next tile's global loads issue before compute
  // (in flight under MFMA), ds_write lands after compute (T14 issue-early/write-late).
  for (int kt = 0; kt < NC; kt += 128) {
    __syncthreads();                                  // buf0 writes visible; buf1 reads done
    if (kt + 64 < NC) load_regs(kt + 64);             // issue next loads early
    compute(As[0], Bs[0]);
    if (kt + 64 < NC) write_lds(As[1], Bs[1]);        // write late -> buf1
    __syncthreads();                                  // buf1 writes visible; buf0 reads done
    if (kt + 128 < NC) load_regs(kt + 128);
    compute(As[1], Bs[1]);
    if (kt + 128 < NC) write_lds(As[0], Bs[0]);       // -> buf0
  }

#pragma unroll
  for (int c = 0; c < 4; c++) {
    const int gcol = n0 + wc * 64 + c * 16 + ln15;
    const int p = gcol >> 10;  // 0=q, 1=k, 2=v
    const int h = (gcol & 1023) >> 6;
    const int hd = gcol & 63;
#pragma unroll
    for (int r = 0; r < 2; r++) {
      const int rbase = m0 + wr * 32 + r * 16 + lq * 4;
#pragma unroll
      for (int g = 0; g < 4; g++) {
        const u16 b = f2b(quantize(acc[r][c][g]));
        const int row = rbase + g;
        if (p == 0)      o0[(h * T_SEQ + row) * HDIM + hd] = b;
        else if (p == 1) o1[(h * T_SEQ + row) * HDIM + hd] = b;
        else             o2[(h * HDIM + hd) * T_SEQ + row] = b;
      }
    }
  }
}

// ---- attention: one block per (64 queries, head); MFMA QK^T and PV ----
__global__ __launch_bounds__(256) void k3_attn(const u16* __restrict__ qh,
                                               const u16* __restrict__ kh,
                                               const u16* __restrict__ vt,
                                               u16* __restrict__ yq) {
  __shared__ __align__(16) u16 S[64 * 328];  // row stride 328 u16 = 656 B
  __shared__ float Linv[64];
  const int tid = threadIdx.x;
  const int lane = tid & 63;
  const int wave = tid >> 6;
  const int ln15 = lane & 15, lq = lane >> 4;
  const int i0 = blockIdx.x * 64;
  const int h = blockIdx.y;
  const int j0 = i0 - 256;  // key col c in [0,320) -> j = j0 + c

  const u16* qb = qh + (h * T_SEQ + i0) * HDIM;
  const u16* kb = kh + h * T_SEQ * HDIM;

  bf16x8 qf[4][2];
#pragma unroll
  for (int r = 0; r < 4; r++) {
    qf[r][0] = *(const bf16x8*)&qb[(r * 16 + ln15) * HDIM + lq * 8];
    qf[r][1] = *(const bf16x8*)&qb[(r * 16 + ln15) * HDIM + 32 + lq * 8];
  }

  // prefetch all K fragments for this wave's 5 column-tiles
  bf16x8 kf[5][2];
#pragma unroll
  for (int t = 0; t < 5; t++) {
    const int jt = j0 + (wave + t * 4) * 16;
    if (jt >= 0) {
      kf[t][0] = *(const bf16x8*)&kb[(jt + ln15) * HDIM + lq * 8];
      kf[t][1] = *(const bf16x8*)&kb[(jt + ln15) * HDIM + 32 + lq * 8];
    } else {
      kf[t][0] = bf16x8{};
      kf[t][1] = bf16x8{};
    }
  }

  // phase 1: scores -> mask -> scale -> quantize -> S (masked = -inf)
#pragma unroll
  for (int t = 0; t < 5; t++) {
    const int ct = wave + t * 4;
    const int jt = j0 + ct * 16;
#pragma unroll
    for (int rt = 0; rt < 4; rt++) {
      const bool skip = (ct < rt) || (ct > rt + 16) || (jt < 0);
      f32x4 s = {0.f, 0.f, 0.f, 0.f};
      if (!skip) {
        s = __builtin_amdgcn_mfma_f32_16x16x32_bf16(qf[rt][0], kf[t][0], s, 0, 0, 0);
        s = __builtin_amdgcn_mfma_f32_16x16x32_bf16(qf[rt][1], kf[t][1], s, 0, 0, 0);
      }
      const int j = jt + ln15;
#pragma unroll
      for (int g = 0; g < 4; g++) {
        const int i = i0 + rt * 16 + lq * 4 + g;
        float v = -INFINITY;
        if (!skip && j <= i && j > i - WINSZ) v = quantize(s[g] * 0.125f);
        S[(rt * 16 + lq * 4 + g) * 328 + ct * 16 + ln15] = f2b(v);
      }
    }
  }
  __syncthreads();

  // phase 2: per-row max + unnormalized exp via b128 LDS I/O; Linv[row] = 1/sum
  {
    const int r = tid >> 2, sg = tid & 3;
    u16* Srow = &S[r * 328 + sg * 80];
    uint4 ch[10];
    float m = -INFINITY;
#pragma unroll
    for (int c = 0; c < 10; c++) {
      ch[c] = *(const uint4*)&Srow[c * 8];
      const u32* w = (const u32*)&ch[c];
#pragma unroll
      for (int d = 0; d < 4; d++) {
        m = fmaxf(m, b2f((u16)(w[d] & 0xffffu)));
        m = fmaxf(m, b2f((u16)(w[d] >> 16)));
      }
    }
    m = fmaxf(m, __shfl_xor(m, 1));
    m = fmaxf(m, __shfl_xor(m, 2));
    float l = 0.0f;
#pragma unroll
    for (int c = 0; c < 10; c++) {
      u32* w = (u32*)&ch[c];
#pragma unroll
      for (int d = 0; d < 4; d++) {
        const float e0 = __expf(b2f((u16)(w[d] & 0xffffu)) - m);
        const float e1 = __expf(b2f((u16)(w[d] >> 16)) - m);
        l += e0 + e1;
        w[d] = ((u32)f2b(e1) << 16) | f2b(e0);
      }
      *(uint4*)&Srow[c * 8] = ch[c];
    }
    l += __shfl_xor(l, 1);
    l += __shfl_xor(l, 2);
    if (sg == 0) Linv[r] = 1.0f / l;
  }
  __syncthreads();

  // phase 3: y = (E @ V^T) * Linv ; wave covers hd block = wave*16; prefetch V
  const u16* vb = vt + (h * HDIM + wave * 16 + ln15) * T_SEQ;
  bf16x8 vf[10];
#pragma unroll
  for (int kk = 0; kk < 10; kk++) {
    int jb = j0 + kk * 32 + lq * 8;
    if (jb < 0) jb = 0;  // unused when masked; keep load in-bounds
    vf[kk] = *(const bf16x8*)&vb[jb];
  }
  f32x4 acc[4] = {};
  const int kk_lo = (i0 < 256) ? ((256 - i0) >> 5) : 0;  // skip j<0 chunks (E=0 there)
  for (int kk = kk_lo; kk < 10; kk++) {
#pragma unroll
    for (int rt = 0; rt < 4; rt++) {
      const bf16x8 pf = *(const bf16x8*)&S[(rt * 16 + ln15) * 328 + kk * 32 + lq * 8];
      acc[rt] = __builtin_amdgcn_mfma_f32_16x16x32_bf16(pf, vf[kk], acc[rt], 0, 0, 0);
    }
  }
#pragma unroll
  for (int rt = 0; rt < 4; rt++)
#pragma unroll
    for (int g = 0; g < 4; g++) {
      const int row = rt * 16 + lq * 4 + g;
      const int i = i0 + row;
      yq[i * NC + h * HDIM + wave * 16 + ln15] = f2b(quantize(acc[rt][g] * Linv[row]));
    }
}

// ---- proj GEMM: 64x64 tile, BK=64, 2-phase dbuf, COALESCED REG-STAGING (same fix as k2) ----
__global__ __launch_bounds__(256, 4) void k4_proj(const u16* __restrict__ A,
                                                  const u16* __restrict__ BT,
                                                  float* __restrict__ of) {
  __shared__ __align__(16) u16 As[2][4096];  // [buf][row:64][slot:8][8]
  __shared__ __align__(16) u16 Bs[2][4096];
  const int tid = threadIdx.x;
  const int lane = tid & 63;
  const int wave = tid >> 6;
  const int wr = wave >> 1, wc = wave & 1;
  const int ln15 = lane & 15, lq = lane >> 4;
  const int l7 = ln15 & 7;
  const int m0 = blockIdx.y * 64, n0 = blockIdx.x * 64;

  // staging: 512 chunks/matrix; 2 per thread; coalesced row=id>>3, sl=id&7
  const u16* ag[2];
  const u16* bg[2];
  int wofs[2];
#pragma unroll
  for (int i = 0; i < 2; i++) {
    const int id = tid + i * 256;
    const int row = id >> 3, sl = id & 7;
    ag[i] = A + (m0 + row) * NC + sl * 8;
    bg[i] = BT + (n0 + row) * NC + sl * 8;
    wofs[i] = (row * 8 + (sl ^ (row & 7))) * 8;
  }

  uint4 ra[2], rb[2];
  f32x4 acc[2][2] = {};

  auto load_regs = [&](int ktv) {
#pragma unroll
    for (int i = 0; i < 2; i++) {
      ra[i] = *(const uint4*)(ag[i] + ktv);
      rb[i] = *(const uint4*)(bg[i] + ktv);
    }
  };
  auto write_lds = [&](u16* LA, u16* LB) {
#pragma unroll
    for (int i = 0; i < 2; i++) {
      *(uint4*)&LA[wofs[i]] = ra[i];
      *(uint4*)&LB[wofs[i]] = rb[i];
    }
  };
  auto compute = [&](const u16* LA, const u16* LB) {
#pragma unroll
    for (int s = 0; s < 2; s++) {
      const int kc = s * 4 + lq;
      const int sw = kc ^ l7;
      bf16x8 af[2], bfr[2];
#pragma unroll
      for (int r = 0; r < 2; r++) {
        const int ar = wr * 32 + r * 16 + ln15;
        af[r] = *(const bf16x8*)&LA[(ar * 8 + sw) * 8];
      }
#pragma unroll
      for (int c = 0; c < 2; c++) {
        const int br = wc * 32 + c * 16 + ln15;
        bfr[c] = *(const bf16x8*)&LB[(br * 8 + sw) * 8];
      }
#pragma unroll
      for (int r = 0; r < 2; r++)
#pragma unroll
        for (int c = 0; c < 2; c++)
          acc[r][c] = __builtin_amdgcn_mfma_f32_16x16x32_bf16(af[r], bfr[c], acc[r][c], 0, 0, 0);
    }
  };

  load_regs(0);
  write_lds(As[0], Bs[0]);

  for (int kt = 0; kt < NC; kt += 128) {
    __syncthreads();
    if (kt + 64 < NC) load_regs(kt + 64);
    compute(As[0], Bs[0]);
    if (kt + 64 < NC) write_lds(As[1], Bs[1]);
    __syncthreads();
    if (kt + 128 < NC) load_regs(kt + 128);
    compute(As[1], Bs[1]);
    if (kt + 128 < NC) write_lds(As[0], Bs[0]);
  }

#pragma unroll
  for (int r = 0; r < 2; r++)
#pragma unroll
    for (int g = 0; g < 4; g++) {
      const int row = m0 + wr * 32 + r * 16 + lq * 4 + g;
#pragma unroll
      for (int c = 0; c < 2; c++)
        of[(long)row * NC + n0 + wc * 32 + c * 16 + ln15] = acc[r][c][g];
    }
}

// ---- launch ----
extern "C" void kernel_launch(void* const* d_in, const int* in_sizes, int n_in,
                              void* d_out, int out_size, void* d_ws, size_t ws_size,
                              hipStream_t stream) {
  // bind by element count (order-robust): x=2M, w_attn=3M, w_proj=1M; dtype fp32 (proven R1-R5)
  const void *px = d_in[0], *pwa = d_in[1], *pwp = d_in[2];
  for (int i = 0; i < n_in; i++) {
    if (in_sizes[i] == 2048 * 1024) px = d_in[i];
    else if (in_sizes[i] == 3072 * 1024) pwa = d_in[i];
    else if (in_sizes[i] == 1024 * 1024) pwp = d_in[i];
  }

  char* ws = (char*)d_ws;
  u16* xb  = (u16*)(ws + (1u << 20));    // [2048][1024]  4 MB
  u16* wTa = (u16*)(ws + (5u << 20));    // [3072][1024]  6 MB
  u16* wTp = (u16*)(ws + (11u << 20));   // [1024][1024]  2 MB
  u16* qh  = (u16*)(ws + (13u << 20));   // [16][2048][64] 4 MB
  u16* kh  = (u16*)(ws + (17u << 20));   // 4 MB
  u16* vt  = (u16*)(ws + (21u << 20));   // [16][64][2048] 4 MB
  u16* yq  = (u16*)(ws + (25u << 20));   // [2048][1024]  4 MB

  k1_prep<<<dim3(48, 16, 3), 256, 0, stream>>>((const float*)px, xb, (const float*)pwa, wTa,
                                               (const float*)pwp, wTp);
  k2_qkv<<<dim3(24, 32), 256, 0, stream>>>(xb, wTa, qh, kh, vt);
  k3_attn<<<dim3(32, 16), 256, 0, stream>>>(qh, kh, vt, yq);
  k4_proj<<<dim3(16, 32), 256, 0, stream>>>(yq, wTp, (float*)d_out);
}

// Round 6
// 141.865 us; speedup vs baseline: 1.4766x; 1.4766x over previous
//
#include <hip/hip_runtime.h>

using u16 = unsigned short;
using u32 = unsigned int;

typedef __bf16 bf16x8 __attribute__((ext_vector_type(8)));
typedef float f32x4 __attribute__((ext_vector_type(4)));

#define T_SEQ 2048
#define NC 1024
#define HDIM 64
#define WINSZ 256
#define QSTEP (2.0f / 255.0f)

__device__ __forceinline__ float b2f(u16 u) {
  u32 v = ((u32)u) << 16;
  return __builtin_bit_cast(float, v);
}
__device__ __forceinline__ u16 f2b(float f) {
  u32 x = __builtin_bit_cast(u32, f);
  u32 r = (x + 0x7fffu + ((x >> 16) & 1u)) >> 16;  // RNE
  return (u16)r;
}
__device__ __forceinline__ float quantize(float v) {
  v = fminf(fmaxf(v, -1.0f), 1.0f);
  return QSTEP * rintf(v / QSTEP);
}

// ---- prep: z=0 transpose w_attn, z=1 transpose w_proj, z=2 convert x (all fp32 -> bf16) ----
__global__ __launch_bounds__(256) void k1_prep(const float* __restrict__ x, u16* __restrict__ xb,
                                               const float* __restrict__ wa, u16* __restrict__ wTa,
                                               const float* __restrict__ wp, u16* __restrict__ wTp) {
  if (blockIdx.z == 2) {  // x convert, vectorized x4, grid-stride
    const int nb = gridDim.x * gridDim.y;
    const int bid = blockIdx.y * gridDim.x + blockIdx.x;
    const int n4 = T_SEQ * NC / 4;
    for (int i = bid * 256 + threadIdx.x; i < n4; i += nb * 256) {
      const float4 v = ((const float4*)x)[i];
      ushort4 o;
      o.x = f2b(v.x); o.y = f2b(v.y); o.z = f2b(v.z); o.w = f2b(v.w);
      ((ushort4*)xb)[i] = o;
    }
    return;
  }
  const int iswp = (blockIdx.z == 1);
  if (iswp && blockIdx.x >= 16) return;
  const float* in = iswp ? wp : wa;
  u16* out = iswp ? wTp : wTa;
  const int Cc = iswp ? 1024 : 3072;
  __shared__ u16 tile[64][65];
  const int tc = blockIdx.x * 64, tr = blockIdx.y * 64;
  const int lx = threadIdx.x & 63, ly = threadIdx.x >> 6;
#pragma unroll
  for (int r = ly; r < 64; r += 4)
    tile[r][lx] = f2b(in[(long)(tr + r) * Cc + tc + lx]);
  __syncthreads();
#pragma unroll
  for (int r = ly; r < 64; r += 4) out[(tc + r) * 1024 + tr + lx] = tile[lx][r];
}

// ---- qkv GEMM: 64x128 tile, BK=64, 2-phase dbuf, coalesced reg-staging (NO arrays/lambdas
// for staging state: R5's uint4 arrays went to scratch -> 163MB HBM writes; named scalars
// + macro code keep them in VGPRs). Chunk map row=tid>>3, sl=tid&7: wave reads 8 rows x
// 128B contiguous = 16 full cache lines/instr. XOR bank-swizzle at ds_write (slot^row&7),
// read slot = kc^(ln15&7); (row+32k)&7==row&7 so the XOR term is per-thread constant. ----
__global__ __launch_bounds__(256, 3) void k2_qkv(const u16* __restrict__ A,
                                                 const u16* __restrict__ BT,
                                                 u16* __restrict__ o0, u16* __restrict__ o1,
                                                 u16* __restrict__ o2) {
  __shared__ __align__(16) u16 As[2][4096];  // [buf][row:64][slot:8][8]   8KB each
  __shared__ __align__(16) u16 Bs[2][8192];  // [buf][row:128][slot:8][8] 16KB each
  const int tid = threadIdx.x;
  const int lane = tid & 63;
  const int wave = tid >> 6;
  const int wr = wave >> 1, wc = wave & 1;  // wave: rows wr*32+[0,32), cols wc*64+[0,64)
  const int ln15 = lane & 15, lq = lane >> 4;
  const int l7 = ln15 & 7;

  // XCD-locality swizzle: 768 blocks, 8 XCDs, 96 contiguous tiles/XCD (bijective: 768%8==0)
  const int wg = blockIdx.y * 24 + blockIdx.x;
  const int lin = (wg & 7) * 96 + (wg >> 3);
  const int by = lin / 24;  // [0,32) M-tile
  const int bx = lin % 24;  // [0,24) N-tile
  const int m0 = by * 64, n0 = bx * 128;

  // staging addresses: chunk (crow, csl); this thread covers rows crow+32k
  const int crow = tid >> 3, csl = tid & 7;
  const u16* ag0 = A + (m0 + crow) * NC + csl * 8;   // + 32*NC for second A chunk
  const u16* bg0 = BT + (n0 + crow) * NC + csl * 8;  // + {32,64,96}*NC for B chunks
  const int wofs = crow * 64 + (csl ^ (crow & 7)) * 8;  // u16 elements; +2048 per 32 rows

  uint4 ra0, ra1, rb0, rb1, rb2, rb3;
  f32x4 acc[2][4] = {};

#define K2_LOAD(KT)                                   \
  {                                                   \
    ra0 = *(const uint4*)(ag0 + (KT));                \
    ra1 = *(const uint4*)(ag0 + 32 * NC + (KT));      \
    rb0 = *(const uint4*)(bg0 + (KT));                \
    rb1 = *(const uint4*)(bg0 + 32 * NC + (KT));      \
    rb2 = *(const uint4*)(bg0 + 64 * NC + (KT));      \
    rb3 = *(const uint4*)(bg0 + 96 * NC + (KT));      \
  }
#define K2_WRITE(BUF)                                 \
  {                                                   \
    *(uint4*)&As[BUF][wofs] = ra0;                    \
    *(uint4*)&As[BUF][wofs + 2048] = ra1;             \
    *(uint4*)&Bs[BUF][wofs] = rb0;                    \
    *(uint4*)&Bs[BUF][wofs + 2048] = rb1;             \
    *(uint4*)&Bs[BUF][wofs + 4096] = rb2;             \
    *(uint4*)&Bs[BUF][wofs + 6144] = rb3;             \
  }

  auto compute = [&](const u16* LA, const u16* LB) {
#pragma unroll
    for (int s = 0; s < 2; s++) {
      const int kc = s * 4 + lq;
      const int sw = kc ^ l7;  // swizzled slot (row&7 == l7 for all fragment rows)
      bf16x8 af[2], bfr[4];
#pragma unroll
      for (int r = 0; r < 2; r++) {
        const int ar = wr * 32 + r * 16 + ln15;
        af[r] = *(const bf16x8*)&LA[(ar * 8 + sw) * 8];
      }
#pragma unroll
      for (int c = 0; c < 4; c++) {
        const int br = wc * 64 + c * 16 + ln15;
        bfr[c] = *(const bf16x8*)&LB[(br * 8 + sw) * 8];
      }
#pragma unroll
      for (int r = 0; r < 2; r++)
#pragma unroll
        for (int c = 0; c < 4; c++)
          acc[r][c] = __builtin_amdgcn_mfma_f32_16x16x32_bf16(af[r], bfr[c], acc[r][c], 0, 0, 0);
    }
  };

  // prologue: tile 0 -> regs -> buf0
  K2_LOAD(0);
  K2_WRITE(0);

  // 2-phase: issue next tile's global loads before compute (in flight under MFMA),
  // ds_write after compute; writes to a buffer always follow a barrier after its last read.
  for (int kt = 0; kt < NC; kt += 128) {
    __syncthreads();  // buf0 writes visible; buf1 reads (prev iter) done
    if (kt + 64 < NC) K2_LOAD(kt + 64);
    compute(As[0], Bs[0]);
    if (kt + 64 < NC) K2_WRITE(1);
    __syncthreads();  // buf1 writes visible; buf0 reads done
    if (kt + 128 < NC) K2_LOAD(kt + 128);
    compute(As[1], Bs[1]);
    if (kt + 128 < NC) K2_WRITE(0);
  }
#undef K2_LOAD
#undef K2_WRITE

#pragma unroll
  for (int c = 0; c < 4; c++) {
    const int gcol = n0 + wc * 64 + c * 16 + ln15;
    const int p = gcol >> 10;  // 0=q, 1=k, 2=v
    const int h = (gcol & 1023) >> 6;
    const int hd = gcol & 63;
#pragma unroll
    for (int r = 0; r < 2; r++) {
      const int rbase = m0 + wr * 32 + r * 16 + lq * 4;
#pragma unroll
      for (int g = 0; g < 4; g++) {
        const u16 b = f2b(quantize(acc[r][c][g]));
        const int row = rbase + g;
        if (p == 0)      o0[(h * T_SEQ + row) * HDIM + hd] = b;
        else if (p == 1) o1[(h * T_SEQ + row) * HDIM + hd] = b;
        else             o2[(h * HDIM + hd) * T_SEQ + row] = b;
      }
    }
  }
}

// ---- attention: one block per (64 queries, head); MFMA QK^T and PV ----
__global__ __launch_bounds__(256) void k3_attn(const u16* __restrict__ qh,
                                               const u16* __restrict__ kh,
                                               const u16* __restrict__ vt,
                                               u16* __restrict__ yq) {
  __shared__ __align__(16) u16 S[64 * 328];  // row stride 328 u16 = 656 B
  __shared__ float Linv[64];
  const int tid = threadIdx.x;
  const int lane = tid & 63;
  const int wave = tid >> 6;
  const int ln15 = lane & 15, lq = lane >> 4;
  const int i0 = blockIdx.x * 64;
  const int h = blockIdx.y;
  const int j0 = i0 - 256;  // key col c in [0,320) -> j = j0 + c

  const u16* qb = qh + (h * T_SEQ + i0) * HDIM;
  const u16* kb = kh + h * T_SEQ * HDIM;

  bf16x8 qf[4][2];
#pragma unroll
  for (int r = 0; r < 4; r++) {
    qf[r][0] = *(const bf16x8*)&qb[(r * 16 + ln15) * HDIM + lq * 8];
    qf[r][1] = *(const bf16x8*)&qb[(r * 16 + ln15) * HDIM + 32 + lq * 8];
  }

  // prefetch all K fragments for this wave's 5 column-tiles
  bf16x8 kf[5][2];
#pragma unroll
  for (int t = 0; t < 5; t++) {
    const int jt = j0 + (wave + t * 4) * 16;
    if (jt >= 0) {
      kf[t][0] = *(const bf16x8*)&kb[(jt + ln15) * HDIM + lq * 8];
      kf[t][1] = *(const bf16x8*)&kb[(jt + ln15) * HDIM + 32 + lq * 8];
    } else {
      kf[t][0] = bf16x8{};
      kf[t][1] = bf16x8{};
    }
  }

  // phase 1: scores -> mask -> scale -> quantize -> S (masked = -inf)
#pragma unroll
  for (int t = 0; t < 5; t++) {
    const int ct = wave + t * 4;
    const int jt = j0 + ct * 16;
#pragma unroll
    for (int rt = 0; rt < 4; rt++) {
      const bool skip = (ct < rt) || (ct > rt + 16) || (jt < 0);
      f32x4 s = {0.f, 0.f, 0.f, 0.f};
      if (!skip) {
        s = __builtin_amdgcn_mfma_f32_16x16x32_bf16(qf[rt][0], kf[t][0], s, 0, 0, 0);
        s = __builtin_amdgcn_mfma_f32_16x16x32_bf16(qf[rt][1], kf[t][1], s, 0, 0, 0);
      }
      const int j = jt + ln15;
#pragma unroll
      for (int g = 0; g < 4; g++) {
        const int i = i0 + rt * 16 + lq * 4 + g;
        float v = -INFINITY;
        if (!skip && j <= i && j > i - WINSZ) v = quantize(s[g] * 0.125f);
        S[(rt * 16 + lq * 4 + g) * 328 + ct * 16 + ln15] = f2b(v);
      }
    }
  }
  __syncthreads();

  // phase 2: per-row max + unnormalized exp via b128 LDS I/O; Linv[row] = 1/sum
  {
    const int r = tid >> 2, sg = tid & 3;
    u16* Srow = &S[r * 328 + sg * 80];
    uint4 ch[10];
    float m = -INFINITY;
#pragma unroll
    for (int c = 0; c < 10; c++) {
      ch[c] = *(const uint4*)&Srow[c * 8];
      const u32* w = (const u32*)&ch[c];
#pragma unroll
      for (int d = 0; d < 4; d++) {
        m = fmaxf(m, b2f((u16)(w[d] & 0xffffu)));
        m = fmaxf(m, b2f((u16)(w[d] >> 16)));
      }
    }
    m = fmaxf(m, __shfl_xor(m, 1));
    m = fmaxf(m, __shfl_xor(m, 2));
    float l = 0.0f;
#pragma unroll
    for (int c = 0; c < 10; c++) {
      u32* w = (u32*)&ch[c];
#pragma unroll
      for (int d = 0; d < 4; d++) {
        const float e0 = __expf(b2f((u16)(w[d] & 0xffffu)) - m);
        const float e1 = __expf(b2f((u16)(w[d] >> 16)) - m);
        l += e0 + e1;
        w[d] = ((u32)f2b(e1) << 16) | f2b(e0);
      }
      *(uint4*)&Srow[c * 8] = ch[c];
    }
    l += __shfl_xor(l, 1);
    l += __shfl_xor(l, 2);
    if (sg == 0) Linv[r] = 1.0f / l;
  }
  __syncthreads();

  // phase 3: y = (E @ V^T) * Linv ; wave covers hd block = wave*16; prefetch V
  const u16* vb = vt + (h * HDIM + wave * 16 + ln15) * T_SEQ;
  bf16x8 vf[10];
#pragma unroll
  for (int kk = 0; kk < 10; kk++) {
    int jb = j0 + kk * 32 + lq * 8;
    if (jb < 0) jb = 0;  // unused when masked; keep load in-bounds
    vf[kk] = *(const bf16x8*)&vb[jb];
  }
  f32x4 acc[4] = {};
  const int kk_lo = (i0 < 256) ? ((256 - i0) >> 5) : 0;  // skip j<0 chunks (E=0 there)
  for (int kk = kk_lo; kk < 10; kk++) {
#pragma unroll
    for (int rt = 0; rt < 4; rt++) {
      const bf16x8 pf = *(const bf16x8*)&S[(rt * 16 + ln15) * 328 + kk * 32 + lq * 8];
      acc[rt] = __builtin_amdgcn_mfma_f32_16x16x32_bf16(pf, vf[kk], acc[rt], 0, 0, 0);
    }
  }
#pragma unroll
  for (int rt = 0; rt < 4; rt++)
#pragma unroll
    for (int g = 0; g < 4; g++) {
      const int row = rt * 16 + lq * 4 + g;
      const int i = i0 + row;
      yq[i * NC + h * HDIM + wave * 16 + ln15] = f2b(quantize(acc[rt][g] * Linv[row]));
    }
}

// ---- proj GEMM: 64x64 tile, BK=64, 2-phase dbuf, coalesced reg-staging (same fix as k2) ----
__global__ __launch_bounds__(256, 4) void k4_proj(const u16* __restrict__ A,
                                                  const u16* __restrict__ BT,
                                                  float* __restrict__ of) {
  __shared__ __align__(16) u16 As[2][4096];  // [buf][row:64][slot:8][8]
  __shared__ __align__(16) u16 Bs[2][4096];
  const int tid = threadIdx.x;
  const int lane = tid & 63;
  const int wave = tid >> 6;
  const int wr = wave >> 1, wc = wave & 1;
  const int ln15 = lane & 15, lq = lane >> 4;
  const int l7 = ln15 & 7;
  const int m0 = blockIdx.y * 64, n0 = blockIdx.x * 64;

  const int crow = tid >> 3, csl = tid & 7;
  const u16* ag0 = A + (m0 + crow) * NC + csl * 8;
  const u16* bg0 = BT + (n0 + crow) * NC + csl * 8;
  const int wofs = crow * 64 + (csl ^ (crow & 7)) * 8;

  uint4 ra0, ra1, rb0, rb1;
  f32x4 acc[2][2] = {};

#define K4_LOAD(KT)                               \
  {                                               \
    ra0 = *(const uint4*)(ag0 + (KT));            \
    ra1 = *(const uint4*)(ag0 + 32 * NC + (KT));  \
    rb0 = *(const uint4*)(bg0 + (KT));            \
    rb1 = *(const uint4*)(bg0 + 32 * NC + (KT));  \
  }
#define K4_WRITE(BUF)                             \
  {                                               \
    *(uint4*)&As[BUF][wofs] = ra0;                \
    *(uint4*)&As[BUF][wofs + 2048] = ra1;         \
    *(uint4*)&Bs[BUF][wofs] = rb0;                \
    *(uint4*)&Bs[BUF][wofs + 2048] = rb1;         \
  }

  auto compute = [&](const u16* LA, const u16* LB) {
#pragma unroll
    for (int s = 0; s < 2; s++) {
      const int kc = s * 4 + lq;
      const int sw = kc ^ l7;
      bf16x8 af[2], bfr[2];
#pragma unroll
      for (int r = 0; r < 2; r++) {
        const int ar = wr * 32 + r * 16 + ln15;
        af[r] = *(const bf16x8*)&LA[(ar * 8 + sw) * 8];
      }
#pragma unroll
      for (int c = 0; c < 2; c++) {
        const int br = wc * 32 + c * 16 + ln15;
        bfr[c] = *(const bf16x8*)&LB[(br * 8 + sw) * 8];
      }
#pragma unroll
      for (int r = 0; r < 2; r++)
#pragma unroll
        for (int c = 0; c < 2; c++)
          acc[r][c] = __builtin_amdgcn_mfma_f32_16x16x32_bf16(af[r], bfr[c], acc[r][c], 0, 0, 0);
    }
  };

  K4_LOAD(0);
  K4_WRITE(0);

  for (int kt = 0; kt < NC; kt += 128) {
    __syncthreads();
    if (kt + 64 < NC) K4_LOAD(kt + 64);
    compute(As[0], Bs[0]);
    if (kt + 64 < NC) K4_WRITE(1);
    __syncthreads();
    if (kt + 128 < NC) K4_LOAD(kt + 128);
    compute(As[1], Bs[1]);
    if (kt + 128 < NC) K4_WRITE(0);
  }
#undef K4_LOAD
#undef K4_WRITE

#pragma unroll
  for (int r = 0; r < 2; r++)
#pragma unroll
    for (int g = 0; g < 4; g++) {
      const int row = m0 + wr * 32 + r * 16 + lq * 4 + g;
#pragma unroll
      for (int c = 0; c < 2; c++)
        of[(long)row * NC + n0 + wc * 32 + c * 16 + ln15] = acc[r][c][g];
    }
}

// ---- launch ----
extern "C" void kernel_launch(void* const* d_in, const int* in_sizes, int n_in,
                              void* d_out, int out_size, void* d_ws, size_t ws_size,
                              hipStream_t stream) {
  // bind by element count (order-robust): x=2M, w_attn=3M, w_proj=1M; dtype fp32 (proven R1-R5)
  const void *px = d_in[0], *pwa = d_in[1], *pwp = d_in[2];
  for (int i = 0; i < n_in; i++) {
    if (in_sizes[i] == 2048 * 1024) px = d_in[i];
    else if (in_sizes[i] == 3072 * 1024) pwa = d_in[i];
    else if (in_sizes[i] == 1024 * 1024) pwp = d_in[i];
  }

  char* ws = (char*)d_ws;
  u16* xb  = (u16*)(ws + (1u << 20));    // [2048][1024]  4 MB
  u16* wTa = (u16*)(ws + (5u << 20));    // [3072][1024]  6 MB
  u16* wTp = (u16*)(ws + (11u << 20));   // [1024][1024]  2 MB
  u16* qh  = (u16*)(ws + (13u << 20));   // [16][2048][64] 4 MB
  u16* kh  = (u16*)(ws + (17u << 20));   // 4 MB
  u16* vt  = (u16*)(ws + (21u << 20));   // [16][64][2048] 4 MB
  u16* yq  = (u16*)(ws + (25u << 20));   // [2048][1024]  4 MB

  k1_prep<<<dim3(48, 16, 3), 256, 0, stream>>>((const float*)px, xb, (const float*)pwa, wTa,
                                               (const float*)pwp, wTp);
  k2_qkv<<<dim3(24, 32), 256, 0, stream>>>(xb, wTa, qh, kh, vt);
  k3_attn<<<dim3(32, 16), 256, 0, stream>>>(qh, kh, vt, yq);
  k4_proj<<<dim3(16, 32), 256, 0, stream>>>(yq, wTp, (float*)d_out);
}

// Round 7
// 128.884 us; speedup vs baseline: 1.6253x; 1.1007x over previous
//
#include <hip/hip_runtime.h>

using u16 = unsigned short;
using u32 = unsigned int;

typedef __bf16 bf16x8 __attribute__((ext_vector_type(8)));
typedef float f32x4 __attribute__((ext_vector_type(4)));

#define T_SEQ 2048
#define NC 1024
#define HDIM 64
#define WINSZ 256
#define QSTEP (2.0f / 255.0f)

__device__ __forceinline__ float b2f(u16 u) {
  u32 v = ((u32)u) << 16;
  return __builtin_bit_cast(float, v);
}
__device__ __forceinline__ u16 f2b(float f) {
  u32 x = __builtin_bit_cast(u32, f);
  u32 r = (x + 0x7fffu + ((x >> 16) & 1u)) >> 16;  // RNE
  return (u16)r;
}
__device__ __forceinline__ float quantize(float v) {
  v = fminf(fmaxf(v, -1.0f), 1.0f);
  return QSTEP * rintf(v / QSTEP);
}

// ---- prep: z=0 transpose w_attn, z=1 transpose w_proj, z=2 convert x (all fp32 -> bf16) ----
__global__ __launch_bounds__(256) void k1_prep(const float* __restrict__ x, u16* __restrict__ xb,
                                               const float* __restrict__ wa, u16* __restrict__ wTa,
                                               const float* __restrict__ wp, u16* __restrict__ wTp) {
  if (blockIdx.z == 2) {  // x convert, vectorized x4, grid-stride
    const int nb = gridDim.x * gridDim.y;
    const int bid = blockIdx.y * gridDim.x + blockIdx.x;
    const int n4 = T_SEQ * NC / 4;
    for (int i = bid * 256 + threadIdx.x; i < n4; i += nb * 256) {
      const float4 v = ((const float4*)x)[i];
      ushort4 o;
      o.x = f2b(v.x); o.y = f2b(v.y); o.z = f2b(v.z); o.w = f2b(v.w);
      ((ushort4*)xb)[i] = o;
    }
    return;
  }
  const int iswp = (blockIdx.z == 1);
  if (iswp && blockIdx.x >= 16) return;
  const float* in = iswp ? wp : wa;
  u16* out = iswp ? wTp : wTa;
  const int Cc = iswp ? 1024 : 3072;
  __shared__ u16 tile[64][65];
  const int tc = blockIdx.x * 64, tr = blockIdx.y * 64;
  const int lx = threadIdx.x & 63, ly = threadIdx.x >> 6;
#pragma unroll
  for (int r = ly; r < 64; r += 4)
    tile[r][lx] = f2b(in[(long)(tr + r) * Cc + tc + lx]);
  __syncthreads();
#pragma unroll
  for (int r = ly; r < 64; r += 4) out[(tc + r) * 1024 + tr + lx] = tile[lx][r];
}

// ---- qkv GEMM: 64x128 tile, BK=64, 2-phase dbuf, coalesced reg-staging (named scalars in
// VGPRs; R5's arrays went to scratch). Chunk map row=tid>>3, sl=tid&7: wave reads 8 rows x
// 128B contiguous = 16 full cache lines/instr. XOR bank-swizzle at ds_write (slot^row&7),
// read slot = kc^(ln15&7). Verified R6: k2 ~48 -> ~24us. ----
__global__ __launch_bounds__(256, 3) void k2_qkv(const u16* __restrict__ A,
                                                 const u16* __restrict__ BT,
                                                 u16* __restrict__ o0, u16* __restrict__ o1,
                                                 u16* __restrict__ o2) {
  __shared__ __align__(16) u16 As[2][4096];  // [buf][row:64][slot:8][8]   8KB each
  __shared__ __align__(16) u16 Bs[2][8192];  // [buf][row:128][slot:8][8] 16KB each
  const int tid = threadIdx.x;
  const int lane = tid & 63;
  const int wave = tid >> 6;
  const int wr = wave >> 1, wc = wave & 1;  // wave: rows wr*32+[0,32), cols wc*64+[0,64)
  const int ln15 = lane & 15, lq = lane >> 4;
  const int l7 = ln15 & 7;

  // XCD-locality swizzle: 768 blocks, 8 XCDs, 96 contiguous tiles/XCD (bijective: 768%8==0)
  const int wg = blockIdx.y * 24 + blockIdx.x;
  const int lin = (wg & 7) * 96 + (wg >> 3);
  const int by = lin / 24;  // [0,32) M-tile
  const int bx = lin % 24;  // [0,24) N-tile
  const int m0 = by * 64, n0 = bx * 128;

  // staging addresses: chunk (crow, csl); this thread covers rows crow+32k
  const int crow = tid >> 3, csl = tid & 7;
  const u16* ag0 = A + (m0 + crow) * NC + csl * 8;   // + 32*NC for second A chunk
  const u16* bg0 = BT + (n0 + crow) * NC + csl * 8;  // + {32,64,96}*NC for B chunks
  const int wofs = crow * 64 + (csl ^ (crow & 7)) * 8;  // u16 elements; +2048 per 32 rows

  uint4 ra0, ra1, rb0, rb1, rb2, rb3;
  f32x4 acc[2][4] = {};

#define K2_LOAD(KT)                                   \
  {                                                   \
    ra0 = *(const uint4*)(ag0 + (KT));                \
    ra1 = *(const uint4*)(ag0 + 32 * NC + (KT));      \
    rb0 = *(const uint4*)(bg0 + (KT));                \
    rb1 = *(const uint4*)(bg0 + 32 * NC + (KT));      \
    rb2 = *(const uint4*)(bg0 + 64 * NC + (KT));      \
    rb3 = *(const uint4*)(bg0 + 96 * NC + (KT));      \
  }
#define K2_WRITE(BUF)                                 \
  {                                                   \
    *(uint4*)&As[BUF][wofs] = ra0;                    \
    *(uint4*)&As[BUF][wofs + 2048] = ra1;             \
    *(uint4*)&Bs[BUF][wofs] = rb0;                    \
    *(uint4*)&Bs[BUF][wofs + 2048] = rb1;             \
    *(uint4*)&Bs[BUF][wofs + 4096] = rb2;             \
    *(uint4*)&Bs[BUF][wofs + 6144] = rb3;             \
  }

  auto compute = [&](const u16* LA, const u16* LB) {
#pragma unroll
    for (int s = 0; s < 2; s++) {
      const int kc = s * 4 + lq;
      const int sw = kc ^ l7;  // swizzled slot (row&7 == l7 for all fragment rows)
      bf16x8 af[2], bfr[4];
#pragma unroll
      for (int r = 0; r < 2; r++) {
        const int ar = wr * 32 + r * 16 + ln15;
        af[r] = *(const bf16x8*)&LA[(ar * 8 + sw) * 8];
      }
#pragma unroll
      for (int c = 0; c < 4; c++) {
        const int br = wc * 64 + c * 16 + ln15;
        bfr[c] = *(const bf16x8*)&LB[(br * 8 + sw) * 8];
      }
#pragma unroll
      for (int r = 0; r < 2; r++)
#pragma unroll
        for (int c = 0; c < 4; c++)
          acc[r][c] = __builtin_amdgcn_mfma_f32_16x16x32_bf16(af[r], bfr[c], acc[r][c], 0, 0, 0);
    }
  };

  // prologue: tile 0 -> regs -> buf0
  K2_LOAD(0);
  K2_WRITE(0);

  for (int kt = 0; kt < NC; kt += 128) {
    __syncthreads();  // buf0 writes visible; buf1 reads (prev iter) done
    if (kt + 64 < NC) K2_LOAD(kt + 64);
    compute(As[0], Bs[0]);
    if (kt + 64 < NC) K2_WRITE(1);
    __syncthreads();  // buf1 writes visible; buf0 reads done
    if (kt + 128 < NC) K2_LOAD(kt + 128);
    compute(As[1], Bs[1]);
    if (kt + 128 < NC) K2_WRITE(0);
  }
#undef K2_LOAD
#undef K2_WRITE

#pragma unroll
  for (int c = 0; c < 4; c++) {
    const int gcol = n0 + wc * 64 + c * 16 + ln15;
    const int p = gcol >> 10;  // 0=q, 1=k, 2=v
    const int h = (gcol & 1023) >> 6;
    const int hd = gcol & 63;
#pragma unroll
    for (int r = 0; r < 2; r++) {
      const int rbase = m0 + wr * 32 + r * 16 + lq * 4;
#pragma unroll
      for (int g = 0; g < 4; g++) {
        const u16 b = f2b(quantize(acc[r][c][g]));
        const int row = rbase + g;
        if (p == 0)      o0[(h * T_SEQ + row) * HDIM + hd] = b;
        else if (p == 1) o1[(h * T_SEQ + row) * HDIM + hd] = b;
        else             o2[(h * HDIM + hd) * T_SEQ + row] = b;
      }
    }
  }
}

// ---- attention: one block per (32 queries, head); grid (64,16)=1024 blocks = 4/CU so
// softmax (VALU) of one block overlaps QK/PV (MFMA) of co-resident blocks (m114 mechanism);
// halved per-block critical path. PV loop fully static (no runtime kk_lo: left-masked
// chunks have E=0 exactly, V loads clamped in-bounds); cols>=288 always masked at QBLK=32
// so PV uses 9 chunks. setprio(1) around MFMA clusters (T5, +4-7% attn per m191). ----
__global__ __launch_bounds__(256, 4) void k3_attn(const u16* __restrict__ qh,
                                                  const u16* __restrict__ kh,
                                                  const u16* __restrict__ vt,
                                                  u16* __restrict__ yq) {
  __shared__ __align__(16) u16 S[32 * 328];  // row stride 328 u16 = 656 B; 20.5 KB
  __shared__ float Linv[32];
  const int tid = threadIdx.x;
  const int lane = tid & 63;
  const int wave = tid >> 6;
  const int ln15 = lane & 15, lq = lane >> 4;
  const int i0 = blockIdx.x * 32;
  const int h = blockIdx.y;
  const int j0 = i0 - 256;  // key col c in [0,320) -> j = j0 + c

  const u16* qb = qh + (h * T_SEQ + i0) * HDIM;
  const u16* kb = kh + h * T_SEQ * HDIM;

  bf16x8 qf[2][2];
#pragma unroll
  for (int r = 0; r < 2; r++) {
    qf[r][0] = *(const bf16x8*)&qb[(r * 16 + ln15) * HDIM + lq * 8];
    qf[r][1] = *(const bf16x8*)&qb[(r * 16 + ln15) * HDIM + 32 + lq * 8];
  }

  // prefetch K fragments for this wave's 5 column-tiles (ct = wave + 4t covers [0,20))
  bf16x8 kf[5][2];
#pragma unroll
  for (int t = 0; t < 5; t++) {
    const int jt = j0 + (wave + t * 4) * 16;
    if (jt >= 0 && jt <= T_SEQ - 16) {
      kf[t][0] = *(const bf16x8*)&kb[(jt + ln15) * HDIM + lq * 8];
      kf[t][1] = *(const bf16x8*)&kb[(jt + ln15) * HDIM + 32 + lq * 8];
    } else {
      kf[t][0] = bf16x8{};
      kf[t][1] = bf16x8{};
    }
  }

  // phase 1: scores -> mask -> scale -> quantize -> S (masked/pad = -inf)
#pragma unroll
  for (int t = 0; t < 5; t++) {
    const int ct = wave + t * 4;
    const int jt = j0 + ct * 16;
#pragma unroll
    for (int rt = 0; rt < 2; rt++) {
      const bool skip = (ct < rt) || (ct > rt + 16) || (jt < 0);
      f32x4 s = {0.f, 0.f, 0.f, 0.f};
      if (!skip) {
        __builtin_amdgcn_s_setprio(1);
        s = __builtin_amdgcn_mfma_f32_16x16x32_bf16(qf[rt][0], kf[t][0], s, 0, 0, 0);
        s = __builtin_amdgcn_mfma_f32_16x16x32_bf16(qf[rt][1], kf[t][1], s, 0, 0, 0);
        __builtin_amdgcn_s_setprio(0);
      }
      const int j = jt + ln15;
#pragma unroll
      for (int g = 0; g < 4; g++) {
        const int i = i0 + rt * 16 + lq * 4 + g;
        float v = -INFINITY;
        if (!skip && j <= i && j > i - WINSZ) v = quantize(s[g] * 0.125f);
        S[(rt * 16 + lq * 4 + g) * 328 + ct * 16 + ln15] = f2b(v);
      }
    }
  }
  __syncthreads();

  // phase 2: per-row max + unnormalized exp; 8 threads/row, 40 u16 each (cols [0,320))
  {
    const int r = tid >> 3, sg = tid & 7;
    u16* Srow = &S[r * 328 + sg * 40];
    uint4 ch[5];
    float m = -INFINITY;
#pragma unroll
    for (int c = 0; c < 5; c++) {
      ch[c] = *(const uint4*)&Srow[c * 8];
      const u32* w = (const u32*)&ch[c];
#pragma unroll
      for (int d = 0; d < 4; d++) {
        m = fmaxf(m, b2f((u16)(w[d] & 0xffffu)));
        m = fmaxf(m, b2f((u16)(w[d] >> 16)));
      }
    }
    m = fmaxf(m, __shfl_xor(m, 1));
    m = fmaxf(m, __shfl_xor(m, 2));
    m = fmaxf(m, __shfl_xor(m, 4));
    float l = 0.0f;
#pragma unroll
    for (int c = 0; c < 5; c++) {
      u32* w = (u32*)&ch[c];
#pragma unroll
      for (int d = 0; d < 4; d++) {
        const float e0 = __expf(b2f((u16)(w[d] & 0xffffu)) - m);
        const float e1 = __expf(b2f((u16)(w[d] >> 16)) - m);
        l += e0 + e1;
        w[d] = ((u32)f2b(e1) << 16) | f2b(e0);
      }
      *(uint4*)&Srow[c * 8] = ch[c];
    }
    l += __shfl_xor(l, 1);
    l += __shfl_xor(l, 2);
    l += __shfl_xor(l, 4);
    if (sg == 0) Linv[r] = 1.0f / l;
  }
  __syncthreads();

  // phase 3: y = (E @ V^T) * Linv; wave covers hd block = wave*16; 9 static kk chunks
  // (cols >= 288 always masked at QBLK=32). Clamped V loads stay in-bounds; masked
  // chunks contribute exactly 0 (E = exp(-inf) = +0, V finite).
  const u16* vb = vt + (h * HDIM + wave * 16 + ln15) * T_SEQ;
  bf16x8 vf[9];
#pragma unroll
  for (int kk = 0; kk < 9; kk++) {
    int jb = j0 + kk * 32 + lq * 8;
    if (jb < 0) jb = 0;
    vf[kk] = *(const bf16x8*)&vb[jb];
  }
  f32x4 acc[2] = {};
#pragma unroll
  for (int kk = 0; kk < 9; kk++) {
#pragma unroll
    for (int rt = 0; rt < 2; rt++) {
      const bf16x8 pf = *(const bf16x8*)&S[(rt * 16 + ln15) * 328 + kk * 32 + lq * 8];
      __builtin_amdgcn_s_setprio(1);
      acc[rt] = __builtin_amdgcn_mfma_f32_16x16x32_bf16(pf, vf[kk], acc[rt], 0, 0, 0);
      __builtin_amdgcn_s_setprio(0);
    }
  }
#pragma unroll
  for (int rt = 0; rt < 2; rt++)
#pragma unroll
    for (int g = 0; g < 4; g++) {
      const int row = rt * 16 + lq * 4 + g;
      const int i = i0 + row;
      yq[i * NC + h * HDIM + wave * 16 + ln15] = f2b(quantize(acc[rt][g] * Linv[row]));
    }
}

// ---- proj GEMM: 64x64 tile, BK=64, 2-phase dbuf, coalesced reg-staging (same as k2) ----
__global__ __launch_bounds__(256, 4) void k4_proj(const u16* __restrict__ A,
                                                  const u16* __restrict__ BT,
                                                  float* __restrict__ of) {
  __shared__ __align__(16) u16 As[2][4096];  // [buf][row:64][slot:8][8]
  __shared__ __align__(16) u16 Bs[2][4096];
  const int tid = threadIdx.x;
  const int lane = tid & 63;
  const int wave = tid >> 6;
  const int wr = wave >> 1, wc = wave & 1;
  const int ln15 = lane & 15, lq = lane >> 4;
  const int l7 = ln15 & 7;
  const int m0 = blockIdx.y * 64, n0 = blockIdx.x * 64;

  const int crow = tid >> 3, csl = tid & 7;
  const u16* ag0 = A + (m0 + crow) * NC + csl * 8;
  const u16* bg0 = BT + (n0 + crow) * NC + csl * 8;
  const int wofs = crow * 64 + (csl ^ (crow & 7)) * 8;

  uint4 ra0, ra1, rb0, rb1;
  f32x4 acc[2][2] = {};

#define K4_LOAD(KT)                               \
  {                                               \
    ra0 = *(const uint4*)(ag0 + (KT));            \
    ra1 = *(const uint4*)(ag0 + 32 * NC + (KT));  \
    rb0 = *(const uint4*)(bg0 + (KT));            \
    rb1 = *(const uint4*)(bg0 + 32 * NC + (KT));  \
  }
#define K4_WRITE(BUF)                             \
  {                                               \
    *(uint4*)&As[BUF][wofs] = ra0;                \
    *(uint4*)&As[BUF][wofs + 2048] = ra1;         \
    *(uint4*)&Bs[BUF][wofs] = rb0;                \
    *(uint4*)&Bs[BUF][wofs + 2048] = rb1;         \
  }

  auto compute = [&](const u16* LA, const u16* LB) {
#pragma unroll
    for (int s = 0; s < 2; s++) {
      const int kc = s * 4 + lq;
      const int sw = kc ^ l7;
      bf16x8 af[2], bfr[2];
#pragma unroll
      for (int r = 0; r < 2; r++) {
        const int ar = wr * 32 + r * 16 + ln15;
        af[r] = *(const bf16x8*)&LA[(ar * 8 + sw) * 8];
      }
#pragma unroll
      for (int c = 0; c < 2; c++) {
        const int br = wc * 32 + c * 16 + ln15;
        bfr[c] = *(const bf16x8*)&LB[(br * 8 + sw) * 8];
      }
#pragma unroll
      for (int r = 0; r < 2; r++)
#pragma unroll
        for (int c = 0; c < 2; c++)
          acc[r][c] = __builtin_amdgcn_mfma_f32_16x16x32_bf16(af[r], bfr[c], acc[r][c], 0, 0, 0);
    }
  };

  K4_LOAD(0);
  K4_WRITE(0);

  for (int kt = 0; kt < NC; kt += 128) {
    __syncthreads();
    if (kt + 64 < NC) K4_LOAD(kt + 64);
    compute(As[0], Bs[0]);
    if (kt + 64 < NC) K4_WRITE(1);
    __syncthreads();
    if (kt + 128 < NC) K4_LOAD(kt + 128);
    compute(As[1], Bs[1]);
    if (kt + 128 < NC) K4_WRITE(0);
  }
#undef K4_LOAD
#undef K4_WRITE

#pragma unroll
  for (int r = 0; r < 2; r++)
#pragma unroll
    for (int g = 0; g < 4; g++) {
      const int row = m0 + wr * 32 + r * 16 + lq * 4 + g;
#pragma unroll
      for (int c = 0; c < 2; c++)
        of[(long)row * NC + n0 + wc * 32 + c * 16 + ln15] = acc[r][c][g];
    }
}

// ---- launch ----
extern "C" void kernel_launch(void* const* d_in, const int* in_sizes, int n_in,
                              void* d_out, int out_size, void* d_ws, size_t ws_size,
                              hipStream_t stream) {
  // bind by element count (order-robust): x=2M, w_attn=3M, w_proj=1M; dtype fp32 (proven R1-R5)
  const void *px = d_in[0], *pwa = d_in[1], *pwp = d_in[2];
  for (int i = 0; i < n_in; i++) {
    if (in_sizes[i] == 2048 * 1024) px = d_in[i];
    else if (in_sizes[i] == 3072 * 1024) pwa = d_in[i];
    else if (in_sizes[i] == 1024 * 1024) pwp = d_in[i];
  }

  char* ws = (char*)d_ws;
  u16* xb  = (u16*)(ws + (1u << 20));    // [2048][1024]  4 MB
  u16* wTa = (u16*)(ws + (5u << 20));    // [3072][1024]  6 MB
  u16* wTp = (u16*)(ws + (11u << 20));   // [1024][1024]  2 MB
  u16* qh  = (u16*)(ws + (13u << 20));   // [16][2048][64] 4 MB
  u16* kh  = (u16*)(ws + (17u << 20));   // 4 MB
  u16* vt  = (u16*)(ws + (21u << 20));   // [16][64][2048] 4 MB
  u16* yq  = (u16*)(ws + (25u << 20));   // [2048][1024]  4 MB

  k1_prep<<<dim3(48, 16, 3), 256, 0, stream>>>((const float*)px, xb, (const float*)pwa, wTa,
                                               (const float*)pwp, wTp);
  k2_qkv<<<dim3(24, 32), 256, 0, stream>>>(xb, wTa, qh, kh, vt);
  k3_attn<<<dim3(64, 16), 256, 0, stream>>>(qh, kh, vt, yq);
  k4_proj<<<dim3(16, 32), 256, 0, stream>>>(yq, wTp, (float*)d_out);
}

// Round 8
// 126.793 us; speedup vs baseline: 1.6521x; 1.0165x over previous
//
#include <hip/hip_runtime.h>

using u16 = unsigned short;
using u32 = unsigned int;

typedef __bf16 bf16x8 __attribute__((ext_vector_type(8)));
typedef float f32x4 __attribute__((ext_vector_type(4)));

#define T_SEQ 2048
#define NC 1024
#define HDIM 64
#define WINSZ 256
#define QSTEP (2.0f / 255.0f)

__device__ __forceinline__ float b2f(u16 u) {
  u32 v = ((u32)u) << 16;
  return __builtin_bit_cast(float, v);
}
__device__ __forceinline__ u16 f2b(float f) {
  u32 x = __builtin_bit_cast(u32, f);
  u32 r = (x + 0x7fffu + ((x >> 16) & 1u)) >> 16;  // RNE
  return (u16)r;
}
__device__ __forceinline__ float quantize(float v) {
  v = fminf(fmaxf(v, -1.0f), 1.0f);
  return QSTEP * rintf(v / QSTEP);
}

// ---- prep: z=0 transpose w_attn, z=1 transpose w_proj, z=2 convert x (all fp32 -> bf16) ----
__global__ __launch_bounds__(256) void k1_prep(const float* __restrict__ x, u16* __restrict__ xb,
                                               const float* __restrict__ wa, u16* __restrict__ wTa,
                                               const float* __restrict__ wp, u16* __restrict__ wTp) {
  if (blockIdx.z == 2) {  // x convert, vectorized x4, grid-stride
    const int nb = gridDim.x * gridDim.y;
    const int bid = blockIdx.y * gridDim.x + blockIdx.x;
    const int n4 = T_SEQ * NC / 4;
    for (int i = bid * 256 + threadIdx.x; i < n4; i += nb * 256) {
      const float4 v = ((const float4*)x)[i];
      ushort4 o;
      o.x = f2b(v.x); o.y = f2b(v.y); o.z = f2b(v.z); o.w = f2b(v.w);
      ((ushort4*)xb)[i] = o;
    }
    return;
  }
  const int iswp = (blockIdx.z == 1);
  if (iswp && blockIdx.x >= 16) return;
  const float* in = iswp ? wp : wa;
  u16* out = iswp ? wTp : wTa;
  const int Cc = iswp ? 1024 : 3072;
  __shared__ u16 tile[64][65];
  const int tc = blockIdx.x * 64, tr = blockIdx.y * 64;
  const int lx = threadIdx.x & 63, ly = threadIdx.x >> 6;
#pragma unroll
  for (int r = ly; r < 64; r += 4)
    tile[r][lx] = f2b(in[(long)(tr + r) * Cc + tc + lx]);
  __syncthreads();
#pragma unroll
  for (int r = ly; r < 64; r += 4) out[(tc + r) * 1024 + tr + lx] = tile[lx][r];
}

// ---- qkv GEMM: 64x128 tile, BK=64, 2-phase dbuf, coalesced reg-staging (named scalars in
// VGPRs; R5's arrays went to scratch). Chunk map row=tid>>3, sl=tid&7: wave reads 8 rows x
// 128B contiguous = 16 full cache lines/instr. XOR bank-swizzle at ds_write (slot^row&7),
// read slot = kc^(ln15&7). Verified R6: k2 ~48 -> ~24us. ----
__global__ __launch_bounds__(256, 3) void k2_qkv(const u16* __restrict__ A,
                                                 const u16* __restrict__ BT,
                                                 u16* __restrict__ o0, u16* __restrict__ o1,
                                                 u16* __restrict__ o2) {
  __shared__ __align__(16) u16 As[2][4096];  // [buf][row:64][slot:8][8]   8KB each
  __shared__ __align__(16) u16 Bs[2][8192];  // [buf][row:128][slot:8][8] 16KB each
  const int tid = threadIdx.x;
  const int lane = tid & 63;
  const int wave = tid >> 6;
  const int wr = wave >> 1, wc = wave & 1;  // wave: rows wr*32+[0,32), cols wc*64+[0,64)
  const int ln15 = lane & 15, lq = lane >> 4;
  const int l7 = ln15 & 7;

  // XCD-locality swizzle: 768 blocks, 8 XCDs, 96 contiguous tiles/XCD (bijective: 768%8==0)
  const int wg = blockIdx.y * 24 + blockIdx.x;
  const int lin = (wg & 7) * 96 + (wg >> 3);
  const int by = lin / 24;  // [0,32) M-tile
  const int bx = lin % 24;  // [0,24) N-tile
  const int m0 = by * 64, n0 = bx * 128;

  // staging addresses: chunk (crow, csl); this thread covers rows crow+32k
  const int crow = tid >> 3, csl = tid & 7;
  const u16* ag0 = A + (m0 + crow) * NC + csl * 8;   // + 32*NC for second A chunk
  const u16* bg0 = BT + (n0 + crow) * NC + csl * 8;  // + {32,64,96}*NC for B chunks
  const int wofs = crow * 64 + (csl ^ (crow & 7)) * 8;  // u16 elements; +2048 per 32 rows

  uint4 ra0, ra1, rb0, rb1, rb2, rb3;
  f32x4 acc[2][4] = {};

#define K2_LOAD(KT)                                   \
  {                                                   \
    ra0 = *(const uint4*)(ag0 + (KT));                \
    ra1 = *(const uint4*)(ag0 + 32 * NC + (KT));      \
    rb0 = *(const uint4*)(bg0 + (KT));                \
    rb1 = *(const uint4*)(bg0 + 32 * NC + (KT));      \
    rb2 = *(const uint4*)(bg0 + 64 * NC + (KT));      \
    rb3 = *(const uint4*)(bg0 + 96 * NC + (KT));      \
  }
#define K2_WRITE(BUF)                                 \
  {                                                   \
    *(uint4*)&As[BUF][wofs] = ra0;                    \
    *(uint4*)&As[BUF][wofs + 2048] = ra1;             \
    *(uint4*)&Bs[BUF][wofs] = rb0;                    \
    *(uint4*)&Bs[BUF][wofs + 2048] = rb1;             \
    *(uint4*)&Bs[BUF][wofs + 4096] = rb2;             \
    *(uint4*)&Bs[BUF][wofs + 6144] = rb3;             \
  }

  auto compute = [&](const u16* LA, const u16* LB) {
#pragma unroll
    for (int s = 0; s < 2; s++) {
      const int kc = s * 4 + lq;
      const int sw = kc ^ l7;  // swizzled slot (row&7 == l7 for all fragment rows)
      bf16x8 af[2], bfr[4];
#pragma unroll
      for (int r = 0; r < 2; r++) {
        const int ar = wr * 32 + r * 16 + ln15;
        af[r] = *(const bf16x8*)&LA[(ar * 8 + sw) * 8];
      }
#pragma unroll
      for (int c = 0; c < 4; c++) {
        const int br = wc * 64 + c * 16 + ln15;
        bfr[c] = *(const bf16x8*)&LB[(br * 8 + sw) * 8];
      }
#pragma unroll
      for (int r = 0; r < 2; r++)
#pragma unroll
        for (int c = 0; c < 4; c++)
          acc[r][c] = __builtin_amdgcn_mfma_f32_16x16x32_bf16(af[r], bfr[c], acc[r][c], 0, 0, 0);
    }
  };

  // prologue: tile 0 -> regs -> buf0
  K2_LOAD(0);
  K2_WRITE(0);

  for (int kt = 0; kt < NC; kt += 128) {
    __syncthreads();  // buf0 writes visible; buf1 reads (prev iter) done
    if (kt + 64 < NC) K2_LOAD(kt + 64);
    compute(As[0], Bs[0]);
    if (kt + 64 < NC) K2_WRITE(1);
    __syncthreads();  // buf1 writes visible; buf0 reads done
    if (kt + 128 < NC) K2_LOAD(kt + 128);
    compute(As[1], Bs[1]);
    if (kt + 128 < NC) K2_WRITE(0);
  }
#undef K2_LOAD
#undef K2_WRITE

#pragma unroll
  for (int c = 0; c < 4; c++) {
    const int gcol = n0 + wc * 64 + c * 16 + ln15;
    const int p = gcol >> 10;  // 0=q, 1=k, 2=v
    const int h = (gcol & 1023) >> 6;
    const int hd = gcol & 63;
#pragma unroll
    for (int r = 0; r < 2; r++) {
      const int rbase = m0 + wr * 32 + r * 16 + lq * 4;
#pragma unroll
      for (int g = 0; g < 4; g++) {
        const u16 b = f2b(quantize(acc[r][c][g]));
        const int row = rbase + g;
        if (p == 0)      o0[(h * T_SEQ + row) * HDIM + hd] = b;
        else if (p == 1) o1[(h * T_SEQ + row) * HDIM + hd] = b;
        else             o2[(h * HDIM + hd) * T_SEQ + row] = b;
      }
    }
  }
}

// ---- attention: one block per (32 queries, head); grid (64,16)=1024 blocks = 4/CU.
// XCD head-grouped swizzle (T1): XCD x owns heads 2x..2x+1 -> per-XCD K/V working set
// 1 MB, L2-resident (was: adjacent Q-blocks of one head scattered across XCDs, every
// XCD re-fetching every head's K/V). 1024%8==0 -> bijective. ----
__global__ __launch_bounds__(256, 4) void k3_attn(const u16* __restrict__ qh,
                                                  const u16* __restrict__ kh,
                                                  const u16* __restrict__ vt,
                                                  u16* __restrict__ yq) {
  __shared__ __align__(16) u16 S[32 * 328];  // row stride 328 u16 = 656 B; 20.5 KB
  __shared__ float Linv[32];
  const int tid = threadIdx.x;
  const int lane = tid & 63;
  const int wave = tid >> 6;
  const int ln15 = lane & 15, lq = lane >> 4;

  // XCD swizzle: g -> lin = (g&7)*128 + g>>3 ; h = lin>>6 (2 heads/XCD), qblk = lin&63
  const int g = blockIdx.y * 64 + blockIdx.x;
  const int lin = (g & 7) * 128 + (g >> 3);
  const int h = lin >> 6;
  const int i0 = (lin & 63) * 32;
  const int j0 = i0 - 256;  // key col c in [0,320) -> j = j0 + c

  const u16* qb = qh + (h * T_SEQ + i0) * HDIM;
  const u16* kb = kh + h * T_SEQ * HDIM;

  bf16x8 qf[2][2];
#pragma unroll
  for (int r = 0; r < 2; r++) {
    qf[r][0] = *(const bf16x8*)&qb[(r * 16 + ln15) * HDIM + lq * 8];
    qf[r][1] = *(const bf16x8*)&qb[(r * 16 + ln15) * HDIM + 32 + lq * 8];
  }

  // prefetch K fragments for this wave's 5 column-tiles (ct = wave + 4t covers [0,20))
  bf16x8 kf[5][2];
#pragma unroll
  for (int t = 0; t < 5; t++) {
    const int jt = j0 + (wave + t * 4) * 16;
    if (jt >= 0 && jt <= T_SEQ - 16) {
      kf[t][0] = *(const bf16x8*)&kb[(jt + ln15) * HDIM + lq * 8];
      kf[t][1] = *(const bf16x8*)&kb[(jt + ln15) * HDIM + 32 + lq * 8];
    } else {
      kf[t][0] = bf16x8{};
      kf[t][1] = bf16x8{};
    }
  }

  // phase 1: scores -> mask -> scale -> quantize -> S (masked/pad = -inf)
#pragma unroll
  for (int t = 0; t < 5; t++) {
    const int ct = wave + t * 4;
    const int jt = j0 + ct * 16;
#pragma unroll
    for (int rt = 0; rt < 2; rt++) {
      const bool skip = (ct < rt) || (ct > rt + 16) || (jt < 0);
      f32x4 s = {0.f, 0.f, 0.f, 0.f};
      if (!skip) {
        __builtin_amdgcn_s_setprio(1);
        s = __builtin_amdgcn_mfma_f32_16x16x32_bf16(qf[rt][0], kf[t][0], s, 0, 0, 0);
        s = __builtin_amdgcn_mfma_f32_16x16x32_bf16(qf[rt][1], kf[t][1], s, 0, 0, 0);
        __builtin_amdgcn_s_setprio(0);
      }
      const int j = jt + ln15;
#pragma unroll
      for (int g2 = 0; g2 < 4; g2++) {
        const int i = i0 + rt * 16 + lq * 4 + g2;
        float v = -INFINITY;
        if (!skip && j <= i && j > i - WINSZ) v = quantize(s[g2] * 0.125f);
        S[(rt * 16 + lq * 4 + g2) * 328 + ct * 16 + ln15] = f2b(v);
      }
    }
  }
  __syncthreads();

  // phase 2: per-row max + unnormalized exp; 8 threads/row, 40 u16 each (cols [0,320))
  {
    const int r = tid >> 3, sg = tid & 7;
    u16* Srow = &S[r * 328 + sg * 40];
    uint4 ch[5];
    float m = -INFINITY;
#pragma unroll
    for (int c = 0; c < 5; c++) {
      ch[c] = *(const uint4*)&Srow[c * 8];
      const u32* w = (const u32*)&ch[c];
#pragma unroll
      for (int d = 0; d < 4; d++) {
        m = fmaxf(m, b2f((u16)(w[d] & 0xffffu)));
        m = fmaxf(m, b2f((u16)(w[d] >> 16)));
      }
    }
    m = fmaxf(m, __shfl_xor(m, 1));
    m = fmaxf(m, __shfl_xor(m, 2));
    m = fmaxf(m, __shfl_xor(m, 4));
    float l = 0.0f;
#pragma unroll
    for (int c = 0; c < 5; c++) {
      u32* w = (u32*)&ch[c];
#pragma unroll
      for (int d = 0; d < 4; d++) {
        const float e0 = __expf(b2f((u16)(w[d] & 0xffffu)) - m);
        const float e1 = __expf(b2f((u16)(w[d] >> 16)) - m);
        l += e0 + e1;
        w[d] = ((u32)f2b(e1) << 16) | f2b(e0);
      }
      *(uint4*)&Srow[c * 8] = ch[c];
    }
    l += __shfl_xor(l, 1);
    l += __shfl_xor(l, 2);
    l += __shfl_xor(l, 4);
    if (sg == 0) Linv[r] = 1.0f / l;
  }
  __syncthreads();

  // phase 3: y = (E @ V^T) * Linv; wave covers hd block = wave*16; 9 static kk chunks
  // (cols >= 288 always masked at QBLK=32). Clamped V loads stay in-bounds; masked
  // chunks contribute exactly 0 (E = exp(-inf) = +0, V finite).
  const u16* vb = vt + (h * HDIM + wave * 16 + ln15) * T_SEQ;
  bf16x8 vf[9];
#pragma unroll
  for (int kk = 0; kk < 9; kk++) {
    int jb = j0 + kk * 32 + lq * 8;
    if (jb < 0) jb = 0;
    vf[kk] = *(const bf16x8*)&vb[jb];
  }
  f32x4 acc[2] = {};
#pragma unroll
  for (int kk = 0; kk < 9; kk++) {
#pragma unroll
    for (int rt = 0; rt < 2; rt++) {
      const bf16x8 pf = *(const bf16x8*)&S[(rt * 16 + ln15) * 328 + kk * 32 + lq * 8];
      __builtin_amdgcn_s_setprio(1);
      acc[rt] = __builtin_amdgcn_mfma_f32_16x16x32_bf16(pf, vf[kk], acc[rt], 0, 0, 0);
      __builtin_amdgcn_s_setprio(0);
    }
  }
#pragma unroll
  for (int rt = 0; rt < 2; rt++)
#pragma unroll
    for (int g2 = 0; g2 < 4; g2++) {
      const int row = rt * 16 + lq * 4 + g2;
      const int i = i0 + row;
      yq[i * NC + h * HDIM + wave * 16 + ln15] = f2b(quantize(acc[rt][g2] * Linv[row]));
    }
}

// ---- proj GEMM: 64x64 tile, BK=64, 2-phase dbuf, coalesced reg-staging (same as k2) ----
__global__ __launch_bounds__(256, 4) void k4_proj(const u16* __restrict__ A,
                                                  const u16* __restrict__ BT,
                                                  float* __restrict__ of) {
  __shared__ __align__(16) u16 As[2][4096];  // [buf][row:64][slot:8][8]
  __shared__ __align__(16) u16 Bs[2][4096];
  const int tid = threadIdx.x;
  const int lane = tid & 63;
  const int wave = tid >> 6;
  const int wr = wave >> 1, wc = wave & 1;
  const int ln15 = lane & 15, lq = lane >> 4;
  const int l7 = ln15 & 7;
  const int m0 = blockIdx.y * 64, n0 = blockIdx.x * 64;

  const int crow = tid >> 3, csl = tid & 7;
  const u16* ag0 = A + (m0 + crow) * NC + csl * 8;
  const u16* bg0 = BT + (n0 + crow) * NC + csl * 8;
  const int wofs = crow * 64 + (csl ^ (crow & 7)) * 8;

  uint4 ra0, ra1, rb0, rb1;
  f32x4 acc[2][2] = {};

#define K4_LOAD(KT)                               \
  {                                               \
    ra0 = *(const uint4*)(ag0 + (KT));            \
    ra1 = *(const uint4*)(ag0 + 32 * NC + (KT));  \
    rb0 = *(const uint4*)(bg0 + (KT));            \
    rb1 = *(const uint4*)(bg0 + 32 * NC + (KT));  \
  }
#define K4_WRITE(BUF)                             \
  {                                               \
    *(uint4*)&As[BUF][wofs] = ra0;                \
    *(uint4*)&As[BUF][wofs + 2048] = ra1;         \
    *(uint4*)&Bs[BUF][wofs] = rb0;                \
    *(uint4*)&Bs[BUF][wofs + 2048] = rb1;         \
  }

  auto compute = [&](const u16* LA, const u16* LB) {
#pragma unroll
    for (int s = 0; s < 2; s++) {
      const int kc = s * 4 + lq;
      const int sw = kc ^ l7;
      bf16x8 af[2], bfr[2];
#pragma unroll
      for (int r = 0; r < 2; r++) {
        const int ar = wr * 32 + r * 16 + ln15;
        af[r] = *(const bf16x8*)&LA[(ar * 8 + sw) * 8];
      }
#pragma unroll
      for (int c = 0; c < 2; c++) {
        const int br = wc * 32 + c * 16 + ln15;
        bfr[c] = *(const bf16x8*)&LB[(br * 8 + sw) * 8];
      }
#pragma unroll
      for (int r = 0; r < 2; r++)
#pragma unroll
        for (int c = 0; c < 2; c++)
          acc[r][c] = __builtin_amdgcn_mfma_f32_16x16x32_bf16(af[r], bfr[c], acc[r][c], 0, 0, 0);
    }
  };

  K4_LOAD(0);
  K4_WRITE(0);

  for (int kt = 0; kt < NC; kt += 128) {
    __syncthreads();
    if (kt + 64 < NC) K4_LOAD(kt + 64);
    compute(As[0], Bs[0]);
    if (kt + 64 < NC) K4_WRITE(1);
    __syncthreads();
    if (kt + 128 < NC) K4_LOAD(kt + 128);
    compute(As[1], Bs[1]);
    if (kt + 128 < NC) K4_WRITE(0);
  }
#undef K4_LOAD
#undef K4_WRITE

#pragma unroll
  for (int r = 0; r < 2; r++)
#pragma unroll
    for (int g = 0; g < 4; g++) {
      const int row = m0 + wr * 32 + r * 16 + lq * 4 + g;
#pragma unroll
      for (int c = 0; c < 2; c++)
        of[(long)row * NC + n0 + wc * 32 + c * 16 + ln15] = acc[r][c][g];
    }
}

// ---- launch ----
extern "C" void kernel_launch(void* const* d_in, const int* in_sizes, int n_in,
                              void* d_out, int out_size, void* d_ws, size_t ws_size,
                              hipStream_t stream) {
  // bind by element count (order-robust): x=2M, w_attn=3M, w_proj=1M; dtype fp32 (proven R1-R5)
  const void *px = d_in[0], *pwa = d_in[1], *pwp = d_in[2];
  for (int i = 0; i < n_in; i++) {
    if (in_sizes[i] == 2048 * 1024) px = d_in[i];
    else if (in_sizes[i] == 3072 * 1024) pwa = d_in[i];
    else if (in_sizes[i] == 1024 * 1024) pwp = d_in[i];
  }

  char* ws = (char*)d_ws;
  u16* xb  = (u16*)(ws + (1u << 20));    // [2048][1024]  4 MB
  u16* wTa = (u16*)(ws + (5u << 20));    // [3072][1024]  6 MB
  u16* wTp = (u16*)(ws + (11u << 20));   // [1024][1024]  2 MB
  u16* qh  = (u16*)(ws + (13u << 20));   // [16][2048][64] 4 MB
  u16* kh  = (u16*)(ws + (17u << 20));   // 4 MB
  u16* vt  = (u16*)(ws + (21u << 20));   // [16][64][2048] 4 MB
  u16* yq  = (u16*)(ws + (25u << 20));   // [2048][1024]  4 MB

  k1_prep<<<dim3(48, 16, 3), 256, 0, stream>>>((const float*)px, xb, (const float*)pwa, wTa,
                                               (const float*)pwp, wTp);
  k2_qkv<<<dim3(24, 32), 256, 0, stream>>>(xb, wTa, qh, kh, vt);
  k3_attn<<<dim3(64, 16), 256, 0, stream>>>(qh, kh, vt, yq);
  k4_proj<<<dim3(16, 32), 256, 0, stream>>>(yq, wTp, (float*)d_out);
}